// Round 4
// baseline (204.247 us; speedup 1.0000x reference)
//
#include <hip/hip_runtime.h>
#include <cstddef>

constexpr int Bn = 16, Dn = 512, Nn = 4096, Kn = 64;
constexpr float FEPS = 1e-12f;

// ---------------------------------------------------------------------------
// kW: transpose conv_w[K][D] -> wT[D][K] so kA can s_load 16 consecutive k.
// ---------------------------------------------------------------------------
__global__ __launch_bounds__(256) void kW(const float* __restrict__ w,
                                          float* __restrict__ wT) {
  const int idx = blockIdx.x * 256 + threadIdx.x;  // 32768 total
  const int d = idx >> 6, k = idx & 63;
  wT[idx] = w[k * Dn + d];
}

// ---------------------------------------------------------------------------
// kA v3: logits GEMM, W broadcast via s_load, x coalesced, no main-loop LDS.
// 512 threads = 8 waves; waves 0-3 -> n-tile 2*nt, waves 4-7 -> 2*nt+1.
// Per wave: 16 k, lane = n, acc[16]. Fused x-norm + softmax + mass partials
// + transposed scaled store asT[b][n][k] = softmax*invn.
//   grid 512: b = bid>>5, nt = bid&31. Occupancy: 4 blocks/CU = 32 waves/CU.
// ---------------------------------------------------------------------------
__global__ __launch_bounds__(512) void kA(const float* __restrict__ x,
                                          const float* __restrict__ wT,
                                          const float* __restrict__ conv_b,
                                          float* __restrict__ asT,
                                          float* __restrict__ massp) {
  __shared__ float red[2][4][64];
  __shared__ float tbuf[2][64][65];  // [grp][n][k], +1 pad
  const int tid = threadIdx.x;
  const int lane = tid & 63;
  const int w = tid >> 6;    // 0..7
  const int grp = w >> 2;    // 0..1 : which n-tile
  const int wl = w & 3;      // 0..3 : k-slice within tile
  const int kg0 = __builtin_amdgcn_readfirstlane(wl << 4);
  const int b = blockIdx.x >> 5;
  const int nt2 = ((blockIdx.x & 31) << 1) + grp;  // 0..63
  const int n0 = nt2 << 6;
  const float* xp = x + (size_t)b * Dn * Nn + n0 + lane;

  float acc[16];
#pragma unroll
  for (int j = 0; j < 16; ++j) acc[j] = 0.f;
  float ss = 0.f;

#pragma unroll 2
  for (int d = 0; d < Dn; d += 4) {
    float xv[4];
#pragma unroll
    for (int i = 0; i < 4; ++i) xv[i] = xp[(size_t)(d + i) * Nn];
    float wv[4][16];
#pragma unroll
    for (int i = 0; i < 4; ++i)
#pragma unroll
      for (int j = 0; j < 16; ++j) wv[i][j] = wT[(d + i) * Kn + kg0 + j];
#pragma unroll
    for (int i = 0; i < 4; ++i) {
      ss = fmaf(xv[i], xv[i], ss);
#pragma unroll
      for (int j = 0; j < 16; ++j) acc[j] = fmaf(wv[i][j], xv[i], acc[j]);
    }
  }

  // ---- epilogue: invn, logits, softmax over K (per 4-wave group) ----
  const float iv = 1.f / fmaxf(sqrtf(ss), FEPS);
  float lg[16];
#pragma unroll
  for (int j = 0; j < 16; ++j) lg[j] = fmaf(acc[j], iv, conv_b[kg0 + j]);
  float pmax = lg[0];
#pragma unroll
  for (int j = 1; j < 16; ++j) pmax = fmaxf(pmax, lg[j]);
  red[grp][wl][lane] = pmax;
  __syncthreads();
  const float gmax = fmaxf(fmaxf(red[grp][0][lane], red[grp][1][lane]),
                           fmaxf(red[grp][2][lane], red[grp][3][lane]));
  __syncthreads();
  float ex[16];
  float psum = 0.f;
#pragma unroll
  for (int j = 0; j < 16; ++j) {
    ex[j] = expf(lg[j] - gmax);
    psum += ex[j];
  }
  red[grp][wl][lane] = psum;
  __syncthreads();
  const float gsum = (red[grp][0][lane] + red[grp][1][lane]) +
                     (red[grp][2][lane] + red[grp][3][lane]);
  const float isum = 1.f / gsum;

  // mass partials (unscaled softmax) + scaled transpose into LDS
#pragma unroll
  for (int j = 0; j < 16; ++j) {
    const float a = ex[j] * isum;
    float m = a;
#pragma unroll
    for (int off = 1; off < 64; off <<= 1) m += __shfl_xor(m, off);
    if (lane == 0) massp[((b << 6) + nt2) * Kn + kg0 + j] = m;
    tbuf[grp][lane][kg0 + j] = a * iv;
  }
  __syncthreads();
  // coalesced write of this grp's [64 n][64 k] tile
  float* atb = asT + ((size_t)b * Nn + n0) * 64;
  const int tid2 = tid & 255;
  const int n = tid2 >> 2, q = (tid2 & 3) << 4;
  float vv[16];
#pragma unroll
  for (int i = 0; i < 16; ++i) vv[i] = tbuf[grp][n][q + i];
#pragma unroll
  for (int u = 0; u < 4; ++u)
    *(float4*)(atb + n * 64 + q + 4 * u) =
        make_float4(vv[4 * u], vv[4 * u + 1], vv[4 * u + 2], vv[4 * u + 3]);
}

// ---------------------------------------------------------------------------
// kB v4: agg GEMM. lane covers TWO d rows (d0, d0+64): 32 FMA per s_load.
//   wave w -> 16 k (s_load_dwordx16 broadcast of asT row), acc[16][2].
//   grid 1024: b = bid>>6, dt = (bid>>4)&3 (128 d), seg = bid&15 (256 n).
// Writes aggp[seg][b][k][d] (16 deterministic partials).
// ---------------------------------------------------------------------------
__global__ __launch_bounds__(256, 4) void kB(const float* __restrict__ x,
                                             const float* __restrict__ asT,
                                             float* __restrict__ aggp) {
  const int tid = threadIdx.x;
  const int lane = tid & 63;
  const int w = tid >> 6;
  const int kg0 = __builtin_amdgcn_readfirstlane(w << 4);
  const int b = blockIdx.x >> 6;
  const int dt = (blockIdx.x >> 4) & 3;
  const int seg = blockIdx.x & 15;
  const int d0 = dt * 128 + lane;
  const float* xp0 = x + (size_t)b * Dn * Nn + (size_t)d0 * Nn + seg * 256;
  const float* xp1 = xp0 + (size_t)64 * Nn;
  const float* arow = asT + ((size_t)b * Nn + seg * 256) * 64 + kg0;

  float acc[16][2];
#pragma unroll
  for (int j = 0; j < 16; ++j) acc[j][0] = acc[j][1] = 0.f;

  for (int nc = 0; nc < 256; nc += 16) {
    float4 q0[4], q1[4];
#pragma unroll
    for (int i = 0; i < 4; ++i) {
      q0[i] = *(const float4*)(xp0 + nc + 4 * i);
      q1[i] = *(const float4*)(xp1 + nc + 4 * i);
    }
    float xa[16], xb[16];
#pragma unroll
    for (int i = 0; i < 4; ++i) {
      xa[4 * i + 0] = q0[i].x; xa[4 * i + 1] = q0[i].y;
      xa[4 * i + 2] = q0[i].z; xa[4 * i + 3] = q0[i].w;
      xb[4 * i + 0] = q1[i].x; xb[4 * i + 1] = q1[i].y;
      xb[4 * i + 2] = q1[i].z; xb[4 * i + 3] = q1[i].w;
    }
#pragma unroll
    for (int t = 0; t < 16; ++t) {
      const float* ar = arow + (size_t)(nc + t) * 64;
#pragma unroll
      for (int j = 0; j < 16; ++j) {
        const float a = ar[j];
        acc[j][0] = fmaf(a, xa[t], acc[j][0]);
        acc[j][1] = fmaf(a, xb[t], acc[j][1]);
      }
    }
  }

  float* outb =
      aggp + (((size_t)(seg * Bn + b)) * Kn + kg0) * Dn + dt * 128 + lane;
#pragma unroll
  for (int j = 0; j < 16; ++j) {
    outb[(size_t)j * Dn] = acc[j][0];
    outb[(size_t)j * Dn + 64] = acc[j][1];
  }
}

// ---------------------------------------------------------------------------
// kC1: per (b,k): mass from massp; vlad = sum(aggp over 16 segs) - mass*c;
// intra-normalize over d.
// ---------------------------------------------------------------------------
__device__ __forceinline__ float blockReduceSum(float v, float* sb) {
#pragma unroll
  for (int off = 32; off > 0; off >>= 1) v += __shfl_down(v, off, 64);
  const int lane = threadIdx.x & 63, w = threadIdx.x >> 6;
  if (lane == 0) sb[w] = v;
  __syncthreads();
  if (threadIdx.x == 0) sb[4] = sb[0] + sb[1] + sb[2] + sb[3];
  __syncthreads();
  return sb[4];
}

__global__ __launch_bounds__(256) void kC1(const float* __restrict__ massp,
                                           const float* __restrict__ aggp,
                                           const float* __restrict__ centroids,
                                           float* __restrict__ out,
                                           float* __restrict__ rowsq) {
  __shared__ float sb[5];
  const int tid = threadIdx.x;
  const int b = blockIdx.x >> 6, k = blockIdx.x & 63;
  float s = 0.f;
  if (tid < 64) s = massp[((b << 6) + tid) * Kn + k];
  const float mass = blockReduceSum(s, sb);
  float v[2];
  float sq = 0.f;
#pragma unroll
  for (int u = 0; u < 2; ++u) {
    const int d = tid + (u << 8);
    float val = -mass * centroids[k * Dn + d];
#pragma unroll
    for (int seg = 0; seg < 16; ++seg)
      val += aggp[(((size_t)seg * Bn + b) * Kn + k) * Dn + d];
    v[u] = val;
    sq = fmaf(val, val, sq);
  }
  const float rsq = blockReduceSum(sq, sb);
  const float inv = 1.f / fmaxf(sqrtf(rsq), FEPS);
#pragma unroll
  for (int u = 0; u < 2; ++u)
    out[((size_t)b * Kn + k) * Dn + tid + (u << 8)] = v[u] * inv;
  if (tid == 0) rowsq[b * Kn + k] = rsq * inv * inv;
}

// ---------------------------------------------------------------------------
// kC2: final global L2 norm per batch.
// ---------------------------------------------------------------------------
__global__ __launch_bounds__(256) void kC2(float* __restrict__ out,
                                           const float* __restrict__ rowsq) {
  __shared__ float sg;
  const int b = blockIdx.x, tid = threadIdx.x;
  float v = (tid < 64) ? rowsq[b * Kn + tid] : 0.f;
  if (tid < 64) {
#pragma unroll
    for (int off = 32; off > 0; off >>= 1) v += __shfl_down(v, off, 64);
  }
  if (tid == 0) sg = 1.f / fmaxf(sqrtf(v), FEPS);
  __syncthreads();
  const float inv = sg;
  float* ob = out + (size_t)b * (Kn * Dn);
  for (int t = tid; t < Kn * Dn; t += 256) ob[t] *= inv;
}

// ---------------------------------------------------------------------------
extern "C" void kernel_launch(void* const* d_in, const int* in_sizes, int n_in,
                              void* d_out, int out_size, void* d_ws,
                              size_t ws_size, hipStream_t stream) {
  const float* x = (const float*)d_in[0];
  const float* centroids = (const float*)d_in[1];
  const float* conv_w = (const float*)d_in[2];
  const float* conv_b = (const float*)d_in[3];
  float* out = (float*)d_out;
  float* ws = (float*)d_ws;
  // ws layout (floats):
  //   asT 4,194,304 | aggp 8,388,608 | rowsq 1,024 | wT 32,768 | massp 65,536
  float* asT = ws;
  float* aggp = ws + 4194304;
  float* rowsq = ws + 12582912;
  float* wT = ws + 12583936;
  float* massp = ws + 12616704;

  kW<<<128, 256, 0, stream>>>(conv_w, wT);
  kA<<<512, 512, 0, stream>>>(x, wT, conv_b, asT, massp);
  kB<<<1024, 256, 0, stream>>>(x, asT, aggp);
  kC1<<<1024, 256, 0, stream>>>(massp, aggp, centroids, out, rowsq);
  kC2<<<16, 256, 0, stream>>>(out, rowsq);
}

// Round 5
// 177.126 us; speedup vs baseline: 1.1531x; 1.1531x over previous
//
#include <hip/hip_runtime.h>
#include <cstddef>

constexpr int Bn = 16, Dn = 512, Nn = 4096, Kn = 64;
constexpr float FEPS = 1e-12f;

typedef __bf16 bf16x8 __attribute__((ext_vector_type(8)));
typedef float f32x4 __attribute__((ext_vector_type(4)));

__device__ __forceinline__ unsigned short f2bf_rne(float f) {
  unsigned u = __float_as_uint(f);
  unsigned r = u + 0x7fffu + ((u >> 16) & 1u);
  return (unsigned short)(r >> 16);
}

// ---------------------------------------------------------------------------
// kW: transpose conv_w[K][D] -> wT[D][K] so kA can s_load 16 consecutive k.
// ---------------------------------------------------------------------------
__global__ __launch_bounds__(256) void kW(const float* __restrict__ w,
                                          float* __restrict__ wT) {
  const int idx = blockIdx.x * 256 + threadIdx.x;  // 32768 total
  const int d = idx >> 6, k = idx & 63;
  wT[idx] = w[k * Dn + d];
}

// ---------------------------------------------------------------------------
// kA: logits GEMM (W via s_load broadcast — wT stays K$-hot), x coalesced.
// Fused x-norm + softmax + mass partials. NEW epilogue: write the scaled
// assignment operand SPLIT into bf16 hi/lo, laid out [b][k][n] (n-contig)
// so kB can load MFMA A-fragments straight from global.
//   grid 512 x 512thr: b = bid>>5; two 64-n tiles per block (grp).
// ---------------------------------------------------------------------------
__global__ __launch_bounds__(512) void kA(const float* __restrict__ x,
                                          const float* __restrict__ wT,
                                          const float* __restrict__ conv_b,
                                          unsigned short* __restrict__ asT_hi,
                                          unsigned short* __restrict__ asT_lo,
                                          float* __restrict__ massp) {
  __shared__ float red[2][4][64];
  __shared__ float tbuf[2][64][65];  // [grp][n][k], +1 pad
  const int tid = threadIdx.x;
  const int lane = tid & 63;
  const int w = tid >> 6;    // 0..7
  const int grp = w >> 2;    // 0..1 : which n-tile
  const int wl = w & 3;      // 0..3 : k-slice within tile
  const int kg0 = __builtin_amdgcn_readfirstlane(wl << 4);
  const int b = blockIdx.x >> 5;
  const int nt2 = ((blockIdx.x & 31) << 1) + grp;  // 0..63
  const int n0 = nt2 << 6;
  const float* xp = x + (size_t)b * Dn * Nn + n0 + lane;

  float acc[16];
#pragma unroll
  for (int j = 0; j < 16; ++j) acc[j] = 0.f;
  float ss = 0.f;

#pragma unroll 2
  for (int d = 0; d < Dn; d += 4) {
    float xv[4];
#pragma unroll
    for (int i = 0; i < 4; ++i) xv[i] = xp[(size_t)(d + i) * Nn];
    float wv[4][16];
#pragma unroll
    for (int i = 0; i < 4; ++i)
#pragma unroll
      for (int j = 0; j < 16; ++j) wv[i][j] = wT[(d + i) * Kn + kg0 + j];
#pragma unroll
    for (int i = 0; i < 4; ++i) {
      ss = fmaf(xv[i], xv[i], ss);
#pragma unroll
      for (int j = 0; j < 16; ++j) acc[j] = fmaf(wv[i][j], xv[i], acc[j]);
    }
  }

  // ---- epilogue: invn, logits, softmax over K (per 4-wave group) ----
  const float iv = 1.f / fmaxf(sqrtf(ss), FEPS);
  float lg[16];
#pragma unroll
  for (int j = 0; j < 16; ++j) lg[j] = fmaf(acc[j], iv, conv_b[kg0 + j]);
  float pmax = lg[0];
#pragma unroll
  for (int j = 1; j < 16; ++j) pmax = fmaxf(pmax, lg[j]);
  red[grp][wl][lane] = pmax;
  __syncthreads();
  const float gmax = fmaxf(fmaxf(red[grp][0][lane], red[grp][1][lane]),
                           fmaxf(red[grp][2][lane], red[grp][3][lane]));
  __syncthreads();
  float ex[16];
  float psum = 0.f;
#pragma unroll
  for (int j = 0; j < 16; ++j) {
    ex[j] = expf(lg[j] - gmax);
    psum += ex[j];
  }
  red[grp][wl][lane] = psum;
  __syncthreads();
  const float gsum = (red[grp][0][lane] + red[grp][1][lane]) +
                     (red[grp][2][lane] + red[grp][3][lane]);
  const float isum = 1.f / gsum;

  // mass partials (fp32 exact) + scaled values into LDS
#pragma unroll
  for (int j = 0; j < 16; ++j) {
    const float a = ex[j] * isum;
    float m = a;
#pragma unroll
    for (int off = 1; off < 64; off <<= 1) m += __shfl_xor(m, off);
    if (lane == 0) massp[((b << 6) + nt2) * Kn + kg0 + j] = m;
    tbuf[grp][lane][kg0 + j] = a * iv;
  }
  __syncthreads();
  // write bf16 hi/lo split, layout [b][k][n]: thread -> (k, 16-n chunk)
  const int tid2 = tid & 255;
  const int k = tid2 & 63;
  const int q = tid2 >> 6;  // 0..3 -> n-chunk q*16
  unsigned hp[8], lp[8];
#pragma unroll
  for (int jj = 0; jj < 8; ++jj) {
    float v0 = tbuf[grp][q * 16 + 2 * jj][k];
    float v1 = tbuf[grp][q * 16 + 2 * jj + 1][k];
    unsigned short h0 = f2bf_rne(v0), h1 = f2bf_rne(v1);
    float l0 = v0 - __uint_as_float((unsigned)h0 << 16);
    float l1 = v1 - __uint_as_float((unsigned)h1 << 16);
    unsigned short g0 = f2bf_rne(l0), g1 = f2bf_rne(l1);
    hp[jj] = (unsigned)h0 | ((unsigned)h1 << 16);
    lp[jj] = (unsigned)g0 | ((unsigned)g1 << 16);
  }
  const size_t abase = ((size_t)b * Kn + k) * Nn + n0 + q * 16;
  uint4* hdst = (uint4*)(asT_hi + abase);
  uint4* ldst = (uint4*)(asT_lo + abase);
  hdst[0] = make_uint4(hp[0], hp[1], hp[2], hp[3]);
  hdst[1] = make_uint4(hp[4], hp[5], hp[6], hp[7]);
  ldst[0] = make_uint4(lp[0], lp[1], lp[2], lp[3]);
  ldst[1] = make_uint4(lp[4], lp[5], lp[6], lp[7]);
}

// ---------------------------------------------------------------------------
// kB v5 (MFMA): agg[k][d] = sum_n A[k,n] * x[d,n], A = asT_hi+asT_lo (bf16
// split of softmax*invn), x converted to bf16 in-register (hi only).
// mfma_f32_16x16x32_bf16: M=k(16), N=d(16), K=n(32).
//   A-frag: lane l -> row m=l&15, k-elems n=(l>>4)*8+j  (16B contig global)
//   B-frag: lane l -> col d=l&15,  k-elems n=(l>>4)*8+j (32B fp32 contig)
//   D:      lane l -> col d=l&15,  row k=(l>>4)*4+r      [m89-verified]
// 512 thr = 8 waves: wave w -> k-slice (w&3)*16, d-half (w>>2)*64 (4 tiles).
// grid 512: b = bid>>5, dt = (bid>>3)&3 (128 d), seg = bid&7 (512 n).
// Writes aggp[seg][b][k][d] (8 deterministic partials).
// ---------------------------------------------------------------------------
__global__ __launch_bounds__(512) void kB(const float* __restrict__ x,
                                          const unsigned short* __restrict__ asT_hi,
                                          const unsigned short* __restrict__ asT_lo,
                                          float* __restrict__ aggp) {
  const int tid = threadIdx.x;
  const int l = tid & 63;
  const int w = tid >> 6;
  const int kw = w & 3;
  const int dh = w >> 2;
  const int b = blockIdx.x >> 5;
  const int dt = (blockIdx.x >> 3) & 3;
  const int seg = blockIdx.x & 7;
  const int lg = l >> 4;        // lane group 0..3
  const int ll = l & 15;

  // A pointers (ushort units)
  const size_t aoff =
      ((size_t)b * Kn + kw * 16 + ll) * Nn + seg * 512 + lg * 8;
  const unsigned short* ah = asT_hi + aoff;
  const unsigned short* al = asT_lo + aoff;
  // B pointers: tile t row d = dt*128 + dh*64 + t*16 + ll
  const int dbase = dt * 128 + dh * 64 + ll;
  const float* xp = x + (size_t)b * Dn * Nn + (size_t)dbase * Nn +
                    seg * 512 + lg * 8;

  f32x4 acc[4];
#pragma unroll
  for (int t = 0; t < 4; ++t) acc[t] = (f32x4){0.f, 0.f, 0.f, 0.f};

  for (int ns = 0; ns < 512; ns += 32) {
    bf16x8 av_h = *(const bf16x8*)(ah + ns);
    bf16x8 av_l = *(const bf16x8*)(al + ns);
#pragma unroll
    for (int t = 0; t < 4; ++t) {
      const float* xr = xp + (size_t)(t * 16) * Nn + ns;
      float4 x0 = *(const float4*)(xr);
      float4 x1 = *(const float4*)(xr + 4);
      bf16x8 bv;
      bv[0] = (__bf16)x0.x; bv[1] = (__bf16)x0.y;
      bv[2] = (__bf16)x0.z; bv[3] = (__bf16)x0.w;
      bv[4] = (__bf16)x1.x; bv[5] = (__bf16)x1.y;
      bv[6] = (__bf16)x1.z; bv[7] = (__bf16)x1.w;
      acc[t] = __builtin_amdgcn_mfma_f32_16x16x32_bf16(av_h, bv, acc[t], 0, 0, 0);
      acc[t] = __builtin_amdgcn_mfma_f32_16x16x32_bf16(av_l, bv, acc[t], 0, 0, 0);
    }
  }

  const int krow = kw * 16 + (lg << 2);
#pragma unroll
  for (int t = 0; t < 4; ++t) {
    const int dcol = dt * 128 + dh * 64 + t * 16 + ll;
    float* op = aggp + (((size_t)(seg * Bn + b)) * Kn + krow) * Dn + dcol;
#pragma unroll
    for (int r = 0; r < 4; ++r) op[(size_t)r * Dn] = acc[t][r];
  }
}

// ---------------------------------------------------------------------------
// kC1: per (b,k): mass from massp; vlad = sum(aggp over 8 segs) - mass*c;
// intra-normalize over d.
// ---------------------------------------------------------------------------
__device__ __forceinline__ float blockReduceSum(float v, float* sb) {
#pragma unroll
  for (int off = 32; off > 0; off >>= 1) v += __shfl_down(v, off, 64);
  const int lane = threadIdx.x & 63, w = threadIdx.x >> 6;
  if (lane == 0) sb[w] = v;
  __syncthreads();
  if (threadIdx.x == 0) sb[4] = sb[0] + sb[1] + sb[2] + sb[3];
  __syncthreads();
  return sb[4];
}

__global__ __launch_bounds__(256) void kC1(const float* __restrict__ massp,
                                           const float* __restrict__ aggp,
                                           const float* __restrict__ centroids,
                                           float* __restrict__ out,
                                           float* __restrict__ rowsq) {
  __shared__ float sb[5];
  const int tid = threadIdx.x;
  const int b = blockIdx.x >> 6, k = blockIdx.x & 63;
  float s = 0.f;
  if (tid < 64) s = massp[((b << 6) + tid) * Kn + k];
  const float mass = blockReduceSum(s, sb);
  float v[2];
  float sq = 0.f;
#pragma unroll
  for (int u = 0; u < 2; ++u) {
    const int d = tid + (u << 8);
    float val = -mass * centroids[k * Dn + d];
#pragma unroll
    for (int seg = 0; seg < 8; ++seg)
      val += aggp[(((size_t)seg * Bn + b) * Kn + k) * Dn + d];
    v[u] = val;
    sq = fmaf(val, val, sq);
  }
  const float rsq = blockReduceSum(sq, sb);
  const float inv = 1.f / fmaxf(sqrtf(rsq), FEPS);
#pragma unroll
  for (int u = 0; u < 2; ++u)
    out[((size_t)b * Kn + k) * Dn + tid + (u << 8)] = v[u] * inv;
  if (tid == 0) rowsq[b * Kn + k] = rsq * inv * inv;
}

// ---------------------------------------------------------------------------
// kC2: final global L2 norm per batch.
// ---------------------------------------------------------------------------
__global__ __launch_bounds__(256) void kC2(float* __restrict__ out,
                                           const float* __restrict__ rowsq) {
  __shared__ float sg;
  const int b = blockIdx.x, tid = threadIdx.x;
  float v = (tid < 64) ? rowsq[b * Kn + tid] : 0.f;
  if (tid < 64) {
#pragma unroll
    for (int off = 32; off > 0; off >>= 1) v += __shfl_down(v, off, 64);
  }
  if (tid == 0) sg = 1.f / fmaxf(sqrtf(v), FEPS);
  __syncthreads();
  const float inv = sg;
  float* ob = out + (size_t)b * (Kn * Dn);
  for (int t = tid; t < Kn * Dn; t += 256) ob[t] *= inv;
}

// ---------------------------------------------------------------------------
extern "C" void kernel_launch(void* const* d_in, const int* in_sizes, int n_in,
                              void* d_out, int out_size, void* d_ws,
                              size_t ws_size, hipStream_t stream) {
  const float* x = (const float*)d_in[0];
  const float* centroids = (const float*)d_in[1];
  const float* conv_w = (const float*)d_in[2];
  const float* conv_b = (const float*)d_in[3];
  float* out = (float*)d_out;
  float* ws = (float*)d_ws;
  // ws layout (float units):
  //   aggp      [0,        4194304)   8 segs x 16 x 64 x 512 f32
  //   asT_hi    [4194304,  6291456)   16x64x4096 bf16 (as 2.1M floats)
  //   asT_lo    [6291456,  8388608)
  //   wT        [8388608,  8421376)
  //   massp     [8421376,  8486912)
  //   rowsq     [8486912,  8487936)
  float* aggp = ws;
  unsigned short* asT_hi = (unsigned short*)(ws + 4194304);
  unsigned short* asT_lo = (unsigned short*)(ws + 6291456);
  float* wT = ws + 8388608;
  float* massp = ws + 8421376;
  float* rowsq = ws + 8486912;

  kW<<<128, 256, 0, stream>>>(conv_w, wT);
  kA<<<512, 512, 0, stream>>>(x, wT, conv_b, asT_hi, asT_lo, massp);
  kB<<<512, 512, 0, stream>>>(x, asT_hi, asT_lo, aggp);
  kC1<<<1024, 256, 0, stream>>>(massp, aggp, centroids, out, rowsq);
  kC2<<<16, 256, 0, stream>>>(out, rowsq);
}

// Round 6
// 176.887 us; speedup vs baseline: 1.1547x; 1.0014x over previous
//
#include <hip/hip_runtime.h>
#include <cstddef>

constexpr int Bn = 16, Dn = 512, Nn = 4096, Kn = 64;
constexpr float FEPS = 1e-12f;

typedef __bf16 bf16x8 __attribute__((ext_vector_type(8)));
typedef float f32x4 __attribute__((ext_vector_type(4)));

__device__ __forceinline__ unsigned short bf_bits(__bf16 h) {
  union { __bf16 b; unsigned short u; } c;
  c.b = h;
  return c.u;
}

// ---------------------------------------------------------------------------
// kW: split conv_w[K][D] (row-major, d-contiguous) into bf16 hi/lo arrays.
// ---------------------------------------------------------------------------
__global__ __launch_bounds__(256) void kW(const float* __restrict__ w,
                                          unsigned short* __restrict__ w_hi,
                                          unsigned short* __restrict__ w_lo) {
  const int idx = blockIdx.x * 256 + threadIdx.x;  // 32768 total
  const float v = w[idx];
  const __bf16 h = (__bf16)v;          // RNE
  const float r = v - (float)h;
  const __bf16 l = (__bf16)r;
  w_hi[idx] = bf_bits(h);
  w_lo[idx] = bf_bits(l);
}

// ---------------------------------------------------------------------------
// kA v4 (MFMA): logits[k][n] = sum_d W[k,d]*x[d,n] via 3-term bf16 split
// (Wh*xh + Wh*xl + Wl*xh), fused x-norm + softmax (all in-register) +
// mass partials + bf16 hi/lo transposed store of softmax*invn.
//   mfma_f32_16x16x32_bf16: M=k(16), N=n(16), K=d(32).
//   A-frag: lane l -> k-row = kt*16+(l&15), d-elems lg*8+j (16B contig) [HW-ok]
//   B-frag: lane l -> n-col = l&15,        d-elems lg*8+j (strided x)
//   D:      lane l -> n-col = l&15,        k-row = kt*16 + lg*4 + r
// grid 1024: b = bid>>6, nt = bid&63 (64-n tile). 256 thr = 4 waves;
// wave wv handles n-subtile wv*16. Each wave computes all 64 k.
// ---------------------------------------------------------------------------
__global__ __launch_bounds__(256) void kA(const float* __restrict__ x,
                                          const unsigned short* __restrict__ w_hi,
                                          const unsigned short* __restrict__ w_lo,
                                          const float* __restrict__ conv_b,
                                          unsigned short* __restrict__ asT_hi,
                                          unsigned short* __restrict__ asT_lo,
                                          float* __restrict__ massp) {
  __shared__ float tbuf[64][65];  // [n][k], +1 pad
  __shared__ float msum[4][64];
  const int tid = threadIdx.x;
  const int l = tid & 63;
  const int wv = tid >> 6;   // wave = n-subtile
  const int ll = l & 15;
  const int lg = l >> 4;
  const int b = blockIdx.x >> 6;
  const int nt = blockIdx.x & 63;
  const int n0 = nt << 6;
  const int n_loc = (wv << 4) + ll;       // n within 64-tile
  const float* xp = x + (size_t)b * Dn * Nn + n0 + n_loc;

  f32x4 acc[4];
#pragma unroll
  for (int kt = 0; kt < 4; ++kt) acc[kt] = (f32x4){0.f, 0.f, 0.f, 0.f};
  float ss = 0.f;

  for (int dc = 0; dc < Dn; dc += 32) {
    const int dbase = dc + lg * 8;
    float xv[8];
#pragma unroll
    for (int j = 0; j < 8; ++j) xv[j] = xp[(size_t)(dbase + j) * Nn];
    bf16x8 bh, bl;
#pragma unroll
    for (int j = 0; j < 8; ++j) {
      ss = fmaf(xv[j], xv[j], ss);
      const __bf16 h = (__bf16)xv[j];          // RNE
      const float r = xv[j] - (float)h;
      bh[j] = h;
      bl[j] = (__bf16)r;
    }
#pragma unroll
    for (int kt = 0; kt < 4; ++kt) {
      const size_t woff = (size_t)(kt * 16 + ll) * Dn + dbase;
      bf16x8 ah = *(const bf16x8*)(w_hi + woff);
      bf16x8 al = *(const bf16x8*)(w_lo + woff);
      acc[kt] = __builtin_amdgcn_mfma_f32_16x16x32_bf16(ah, bh, acc[kt], 0, 0, 0);
      acc[kt] = __builtin_amdgcn_mfma_f32_16x16x32_bf16(ah, bl, acc[kt], 0, 0, 0);
      acc[kt] = __builtin_amdgcn_mfma_f32_16x16x32_bf16(al, bh, acc[kt], 0, 0, 0);
    }
  }

  // ---- full ss per n (reduce across lane-groups; lanes w/ same ll share n)
  ss += __shfl_xor(ss, 16);
  ss += __shfl_xor(ss, 32);
  const float iv = 1.f / fmaxf(sqrtf(ss), FEPS);

  // ---- logits: lane holds k = kt*16 + lg*4 + r, n = n0 + n_loc
  float lgt[16];
#pragma unroll
  for (int kt = 0; kt < 4; ++kt)
#pragma unroll
    for (int r = 0; r < 4; ++r)
      lgt[kt * 4 + r] =
          fmaf(acc[kt][r], iv, conv_b[kt * 16 + lg * 4 + r]);

  // ---- softmax over all 64 k: in-lane 16 + cross-lane over lg axis
  float pmax = lgt[0];
#pragma unroll
  for (int i = 1; i < 16; ++i) pmax = fmaxf(pmax, lgt[i]);
  pmax = fmaxf(pmax, __shfl_xor(pmax, 16));
  pmax = fmaxf(pmax, __shfl_xor(pmax, 32));
  float ex[16];
  float psum = 0.f;
#pragma unroll
  for (int i = 0; i < 16; ++i) {
    ex[i] = expf(lgt[i] - pmax);
    psum += ex[i];
  }
  psum += __shfl_xor(psum, 16);
  psum += __shfl_xor(psum, 32);
  const float isum = 1.f / psum;

  // ---- write a*iv into tbuf; mass partials (unscaled a) per k
#pragma unroll
  for (int i = 0; i < 16; ++i) {
    const int k = (i >> 2) * 16 + lg * 4 + (i & 3);
    const float a = ex[i] * isum;
    tbuf[n_loc][k] = a * iv;
    float m = a;
    m += __shfl_xor(m, 1);
    m += __shfl_xor(m, 2);
    m += __shfl_xor(m, 4);
    m += __shfl_xor(m, 8);
    if (ll == 0) msum[wv][k] = m;
  }
  __syncthreads();

  if (tid < 64)
    massp[((b << 6) + nt) * Kn + tid] =
        (msum[0][tid] + msum[1][tid]) + (msum[2][tid] + msum[3][tid]);

  // ---- bf16 hi/lo split store, layout [b][k][n]: thread -> (k, 16-n chunk)
  const int k = tid & 63;
  const int q = tid >> 6;  // n-chunk q*16
  unsigned hp[8], lp[8];
#pragma unroll
  for (int jj = 0; jj < 8; ++jj) {
    float v0 = tbuf[q * 16 + 2 * jj][k];
    float v1 = tbuf[q * 16 + 2 * jj + 1][k];
    const __bf16 h0 = (__bf16)v0, h1 = (__bf16)v1;
    float l0 = v0 - (float)h0;
    float l1 = v1 - (float)h1;
    const __bf16 g0 = (__bf16)l0, g1 = (__bf16)l1;
    hp[jj] = (unsigned)bf_bits(h0) | ((unsigned)bf_bits(h1) << 16);
    lp[jj] = (unsigned)bf_bits(g0) | ((unsigned)bf_bits(g1) << 16);
  }
  const size_t abase = ((size_t)b * Kn + k) * Nn + n0 + q * 16;
  uint4* hdst = (uint4*)(asT_hi + abase);
  uint4* ldst = (uint4*)(asT_lo + abase);
  hdst[0] = make_uint4(hp[0], hp[1], hp[2], hp[3]);
  hdst[1] = make_uint4(hp[4], hp[5], hp[6], hp[7]);
  ldst[0] = make_uint4(lp[0], lp[1], lp[2], lp[3]);
  ldst[1] = make_uint4(lp[4], lp[5], lp[6], lp[7]);
}

// ---------------------------------------------------------------------------
// kB v5 (MFMA): agg[k][d] = sum_n A[k,n] * x[d,n], A = asT_hi+asT_lo (bf16
// split of softmax*invn), x converted to bf16 in-register (hi only).
//   (validated round 5: absmax unchanged)
// ---------------------------------------------------------------------------
__global__ __launch_bounds__(512) void kB(const float* __restrict__ x,
                                          const unsigned short* __restrict__ asT_hi,
                                          const unsigned short* __restrict__ asT_lo,
                                          float* __restrict__ aggp) {
  const int tid = threadIdx.x;
  const int l = tid & 63;
  const int w = tid >> 6;
  const int kw = w & 3;
  const int dh = w >> 2;
  const int b = blockIdx.x >> 5;
  const int dt = (blockIdx.x >> 3) & 3;
  const int seg = blockIdx.x & 7;
  const int lg = l >> 4;
  const int ll = l & 15;

  const size_t aoff =
      ((size_t)b * Kn + kw * 16 + ll) * Nn + seg * 512 + lg * 8;
  const unsigned short* ah = asT_hi + aoff;
  const unsigned short* al = asT_lo + aoff;
  const int dbase = dt * 128 + dh * 64 + ll;
  const float* xp = x + (size_t)b * Dn * Nn + (size_t)dbase * Nn +
                    seg * 512 + lg * 8;

  f32x4 acc[4];
#pragma unroll
  for (int t = 0; t < 4; ++t) acc[t] = (f32x4){0.f, 0.f, 0.f, 0.f};

  for (int ns = 0; ns < 512; ns += 32) {
    bf16x8 av_h = *(const bf16x8*)(ah + ns);
    bf16x8 av_l = *(const bf16x8*)(al + ns);
#pragma unroll
    for (int t = 0; t < 4; ++t) {
      const float* xr = xp + (size_t)(t * 16) * Nn + ns;
      float4 x0 = *(const float4*)(xr);
      float4 x1 = *(const float4*)(xr + 4);
      bf16x8 bv;
      bv[0] = (__bf16)x0.x; bv[1] = (__bf16)x0.y;
      bv[2] = (__bf16)x0.z; bv[3] = (__bf16)x0.w;
      bv[4] = (__bf16)x1.x; bv[5] = (__bf16)x1.y;
      bv[6] = (__bf16)x1.z; bv[7] = (__bf16)x1.w;
      acc[t] = __builtin_amdgcn_mfma_f32_16x16x32_bf16(av_h, bv, acc[t], 0, 0, 0);
      acc[t] = __builtin_amdgcn_mfma_f32_16x16x32_bf16(av_l, bv, acc[t], 0, 0, 0);
    }
  }

  const int krow = kw * 16 + (lg << 2);
#pragma unroll
  for (int t = 0; t < 4; ++t) {
    const int dcol = dt * 128 + dh * 64 + t * 16 + ll;
    float* op = aggp + (((size_t)(seg * Bn + b)) * Kn + krow) * Dn + dcol;
#pragma unroll
    for (int r = 0; r < 4; ++r) op[(size_t)r * Dn] = acc[t][r];
  }
}

// ---------------------------------------------------------------------------
// kC1: per (b,k): mass from massp; vlad = sum(aggp over 8 segs) - mass*c;
// intra-normalize over d.
// ---------------------------------------------------------------------------
__device__ __forceinline__ float blockReduceSum(float v, float* sb) {
#pragma unroll
  for (int off = 32; off > 0; off >>= 1) v += __shfl_down(v, off, 64);
  const int lane = threadIdx.x & 63, w = threadIdx.x >> 6;
  if (lane == 0) sb[w] = v;
  __syncthreads();
  if (threadIdx.x == 0) sb[4] = sb[0] + sb[1] + sb[2] + sb[3];
  __syncthreads();
  return sb[4];
}

__global__ __launch_bounds__(256) void kC1(const float* __restrict__ massp,
                                           const float* __restrict__ aggp,
                                           const float* __restrict__ centroids,
                                           float* __restrict__ out,
                                           float* __restrict__ rowsq) {
  __shared__ float sb[5];
  const int tid = threadIdx.x;
  const int b = blockIdx.x >> 6, k = blockIdx.x & 63;
  float s = 0.f;
  if (tid < 64) s = massp[((b << 6) + tid) * Kn + k];
  const float mass = blockReduceSum(s, sb);
  float v[2];
  float sq = 0.f;
#pragma unroll
  for (int u = 0; u < 2; ++u) {
    const int d = tid + (u << 8);
    float val = -mass * centroids[k * Dn + d];
#pragma unroll
    for (int seg = 0; seg < 8; ++seg)
      val += aggp[(((size_t)seg * Bn + b) * Kn + k) * Dn + d];
    v[u] = val;
    sq = fmaf(val, val, sq);
  }
  const float rsq = blockReduceSum(sq, sb);
  const float inv = 1.f / fmaxf(sqrtf(rsq), FEPS);
#pragma unroll
  for (int u = 0; u < 2; ++u)
    out[((size_t)b * Kn + k) * Dn + tid + (u << 8)] = v[u] * inv;
  if (tid == 0) rowsq[b * Kn + k] = rsq * inv * inv;
}

// ---------------------------------------------------------------------------
// kC2: final global L2 norm per batch.
// ---------------------------------------------------------------------------
__global__ __launch_bounds__(256) void kC2(float* __restrict__ out,
                                           const float* __restrict__ rowsq) {
  __shared__ float sg;
  const int b = blockIdx.x, tid = threadIdx.x;
  float v = (tid < 64) ? rowsq[b * Kn + tid] : 0.f;
  if (tid < 64) {
#pragma unroll
    for (int off = 32; off > 0; off >>= 1) v += __shfl_down(v, off, 64);
  }
  if (tid == 0) sg = 1.f / fmaxf(sqrtf(v), FEPS);
  __syncthreads();
  const float inv = sg;
  float* ob = out + (size_t)b * (Kn * Dn);
  for (int t = tid; t < Kn * Dn; t += 256) ob[t] *= inv;
}

// ---------------------------------------------------------------------------
extern "C" void kernel_launch(void* const* d_in, const int* in_sizes, int n_in,
                              void* d_out, int out_size, void* d_ws,
                              size_t ws_size, hipStream_t stream) {
  const float* x = (const float*)d_in[0];
  const float* centroids = (const float*)d_in[1];
  const float* conv_w = (const float*)d_in[2];
  const float* conv_b = (const float*)d_in[3];
  float* out = (float*)d_out;
  float* ws = (float*)d_ws;
  // ws layout (float units):
  //   aggp      [0,        4194304)   8 segs x 16 x 64 x 512 f32
  //   asT_hi    [4194304,  6291456)   16x64x4096 bf16
  //   asT_lo    [6291456,  8388608)
  //   w_hi      [8388608,  8404992)   64x512 bf16
  //   w_lo      [8404992,  8421376)
  //   massp     [8421376,  8486912)
  //   rowsq     [8486912,  8487936)
  float* aggp = ws;
  unsigned short* asT_hi = (unsigned short*)(ws + 4194304);
  unsigned short* asT_lo = (unsigned short*)(ws + 6291456);
  unsigned short* w_hi = (unsigned short*)(ws + 8388608);
  unsigned short* w_lo = (unsigned short*)(ws + 8404992);
  float* massp = ws + 8421376;
  float* rowsq = ws + 8486912;

  kW<<<128, 256, 0, stream>>>(conv_w, w_hi, w_lo);
  kA<<<1024, 256, 0, stream>>>(x, w_hi, w_lo, conv_b, asT_hi, asT_lo, massp);
  kB<<<512, 512, 0, stream>>>(x, asT_hi, asT_lo, aggp);
  kC1<<<1024, 256, 0, stream>>>(massp, aggp, centroids, out, rowsq);
  kC2<<<16, 256, 0, stream>>>(out, rowsq);
}

// Round 8
// 170.097 us; speedup vs baseline: 1.2008x; 1.0399x over previous
//
#include <hip/hip_runtime.h>
#include <cstddef>

constexpr int Bn = 16, Dn = 512, Nn = 4096, Kn = 64;
constexpr int Np = 4224;   // padded asT pitch (elements): 8448 B, non-pow2
constexpr int Dp = 528;    // padded aggp pitch (elements): 2112 B, non-pow2
constexpr float FEPS = 1e-12f;

typedef __bf16 bf16x8 __attribute__((ext_vector_type(8)));
typedef float f32x4 __attribute__((ext_vector_type(4)));

__device__ __forceinline__ unsigned short bf_bits(__bf16 h) {
  union { __bf16 b; unsigned short u; } c;
  c.b = h;
  return c.u;
}

// ---------------------------------------------------------------------------
// kW: split conv_w[K][D] (row-major, d-contiguous) into bf16 hi/lo arrays.
// ---------------------------------------------------------------------------
__global__ __launch_bounds__(256) void kW(const float* __restrict__ w,
                                          unsigned short* __restrict__ w_hi,
                                          unsigned short* __restrict__ w_lo) {
  const int idx = blockIdx.x * 256 + threadIdx.x;  // 32768 total
  const float v = w[idx];
  const __bf16 h = (__bf16)v;          // RNE
  const float r = v - (float)h;
  const __bf16 l = (__bf16)r;
  w_hi[idx] = bf_bits(h);
  w_lo[idx] = bf_bits(l);
}

// ---------------------------------------------------------------------------
// kA v6 (MFMA + LDS transpose staging): logits[k][n] = sum_d W[k,d]*x[d,n]
// via 3-term bf16 split; fused x-norm + softmax + mass partials + bf16 hi/lo
// store of softmax*invn at padded pitch Np.
//   x read in FULL 1KB contiguous rows (kills 16KB-pow2-stride channel
//   camping), transposed through LDS (pitch 33), register-double-buffered.
//   LDS: xs (8448 f) and tw (17152 f) share one buffer (disjoint phases),
//   70.7 KB total -> 2 blocks/CU.
// grid 256: b = bid>>4, panel p = bid&15 (256 n). 512 thr = 8 waves;
// wave w owns n-subpanel w*32; per wave 2 sub-tiles of 16 n, all 64 k.
// ---------------------------------------------------------------------------
__global__ __launch_bounds__(512) void kA(const float* __restrict__ x,
                                          const unsigned short* __restrict__ w_hi,
                                          const unsigned short* __restrict__ w_lo,
                                          const float* __restrict__ conv_b,
                                          unsigned short* __restrict__ asT_hi,
                                          unsigned short* __restrict__ asT_lo,
                                          float* __restrict__ massp) {
  __shared__ float smem[8 * 32 * 67];  // epilogue: tw[8][32][67]; loop: xs[256*33]
  __shared__ float msum[8][64];
  float* const xs = smem;              // [col 256][row 32+1pad]
  const int tid = threadIdx.x;
  const int l = tid & 63;
  const int w = tid >> 6;    // 0..7
  const int ll = l & 15;
  const int lg = l >> 4;
  const int b = blockIdx.x >> 4;
  const int p = blockIdx.x & 15;
  const int n0 = p << 8;
  const float* xb = x + (size_t)b * Dn * Nn + n0;

  f32x4 acc[4][2];
#pragma unroll
  for (int kt = 0; kt < 4; ++kt)
#pragma unroll
    for (int s = 0; s < 2; ++s) acc[kt][s] = (f32x4){0.f, 0.f, 0.f, 0.f};
  float ss[2] = {0.f, 0.f};

  // prefetch chunk 0: wave w loads rows {w, w+8, w+16, w+24}, lane sweeps row
  float pf[4][4];
#pragma unroll
  for (int i = 0; i < 4; ++i)
#pragma unroll
    for (int q = 0; q < 4; ++q)
      pf[i][q] = xb[(size_t)(w + 8 * i) * Nn + l + 64 * q];

  for (int dc = 0; dc < Dn; dc += 32) {
    __syncthreads();  // xs free (previous chunk consumed)
#pragma unroll
    for (int i = 0; i < 4; ++i)
#pragma unroll
      for (int q = 0; q < 4; ++q)
        xs[(l + 64 * q) * 33 + w + 8 * i] = pf[i][q];
    if (dc + 32 < Dn) {
#pragma unroll
      for (int i = 0; i < 4; ++i)
#pragma unroll
        for (int q = 0; q < 4; ++q)
          pf[i][q] = xb[(size_t)(dc + 32 + w + 8 * i) * Nn + l + 64 * q];
    }
    __syncthreads();  // xs ready

    // A-frags (W) once per chunk, shared across both n-subtiles
    bf16x8 ah[4], al[4];
#pragma unroll
    for (int kt = 0; kt < 4; ++kt) {
      const size_t woff = (size_t)(kt * 16 + ll) * Dn + dc + lg * 8;
      ah[kt] = *(const bf16x8*)(w_hi + woff);
      al[kt] = *(const bf16x8*)(w_lo + woff);
    }
#pragma unroll
    for (int sub = 0; sub < 2; ++sub) {
      const int ncol = (w << 5) + (sub << 4) + ll;
      float xv[8];
#pragma unroll
      for (int j = 0; j < 8; ++j) xv[j] = xs[ncol * 33 + lg * 8 + j];
      bf16x8 bh, bl;
#pragma unroll
      for (int j = 0; j < 8; ++j) {
        ss[sub] = fmaf(xv[j], xv[j], ss[sub]);
        const __bf16 h = (__bf16)xv[j];
        bh[j] = h;
        bl[j] = (__bf16)(xv[j] - (float)h);
      }
#pragma unroll
      for (int kt = 0; kt < 4; ++kt) {
        acc[kt][sub] =
            __builtin_amdgcn_mfma_f32_16x16x32_bf16(ah[kt], bh, acc[kt][sub], 0, 0, 0);
        acc[kt][sub] =
            __builtin_amdgcn_mfma_f32_16x16x32_bf16(ah[kt], bl, acc[kt][sub], 0, 0, 0);
        acc[kt][sub] =
            __builtin_amdgcn_mfma_f32_16x16x32_bf16(al[kt], bh, acc[kt][sub], 0, 0, 0);
      }
    }
  }

  // ---- epilogue ----
  float ivs[2];
#pragma unroll
  for (int sub = 0; sub < 2; ++sub) {
    float s2 = ss[sub];
    s2 += __shfl_xor(s2, 16);
    s2 += __shfl_xor(s2, 32);
    ivs[sub] = 1.f / fmaxf(sqrtf(s2), FEPS);
  }
  float cbv[16];
#pragma unroll
  for (int i = 0; i < 16; ++i) cbv[i] = conv_b[(i >> 2) * 16 + lg * 4 + (i & 3)];
  float mk[16];
#pragma unroll
  for (int i = 0; i < 16; ++i) mk[i] = 0.f;

  __syncthreads();  // all xs reads done before smem is reused as tw
  float* twp = smem + w * (32 * 67);
#pragma unroll
  for (int sub = 0; sub < 2; ++sub) {
    float lgt[16];
#pragma unroll
    for (int kt = 0; kt < 4; ++kt)
#pragma unroll
      for (int r = 0; r < 4; ++r)
        lgt[kt * 4 + r] = fmaf(acc[kt][sub][r], ivs[sub], cbv[kt * 4 + r]);
    float pmax = lgt[0];
#pragma unroll
    for (int i = 1; i < 16; ++i) pmax = fmaxf(pmax, lgt[i]);
    pmax = fmaxf(pmax, __shfl_xor(pmax, 16));
    pmax = fmaxf(pmax, __shfl_xor(pmax, 32));
    float ex[16];
    float psum = 0.f;
#pragma unroll
    for (int i = 0; i < 16; ++i) {
      ex[i] = expf(lgt[i] - pmax);
      psum += ex[i];
    }
    psum += __shfl_xor(psum, 16);
    psum += __shfl_xor(psum, 32);
    const float isum = 1.f / psum;
#pragma unroll
    for (int i = 0; i < 16; ++i) {
      const int kslot = (i >> 2) * 16 + lg * 4 + (i & 3);
      const float a = ex[i] * isum;
      twp[(sub * 16 + ll) * 67 + kslot] = a * ivs[sub];
      float m = a;
      m += __shfl_xor(m, 1);
      m += __shfl_xor(m, 2);
      m += __shfl_xor(m, 4);
      m += __shfl_xor(m, 8);
      mk[i] += m;
    }
  }
  if (ll == 0) {
#pragma unroll
    for (int i = 0; i < 16; ++i)
      msum[w][(i >> 2) * 16 + lg * 4 + (i & 3)] = mk[i];
  }
  __syncthreads();
  if (tid < 64) {
    float s = 0.f;
#pragma unroll
    for (int ww = 0; ww < 8; ++ww) s += msum[ww][tid];
    massp[((b << 4) + p) * Kn + tid] = s;
  }

  // ---- asT hi/lo write: lane = k-row, 32 n of this wave, padded pitch Np
  {
    const int k = l;
    unsigned hp[16], lp[16];
#pragma unroll
    for (int n = 0; n < 32; n += 2) {
      const float v0 = twp[n * 67 + k];
      const float v1 = twp[(n + 1) * 67 + k];
      const __bf16 h0 = (__bf16)v0, h1 = (__bf16)v1;
      const __bf16 g0 = (__bf16)(v0 - (float)h0), g1 = (__bf16)(v1 - (float)h1);
      hp[n >> 1] = (unsigned)bf_bits(h0) | ((unsigned)bf_bits(h1) << 16);
      lp[n >> 1] = (unsigned)bf_bits(g0) | ((unsigned)bf_bits(g1) << 16);
    }
    const size_t abase = ((size_t)b * Kn + k) * Np + n0 + (w << 5);
    uint4* hd = (uint4*)(asT_hi + abase);
    uint4* ld = (uint4*)(asT_lo + abase);
#pragma unroll
    for (int u = 0; u < 4; ++u) {
      hd[u] = make_uint4(hp[4 * u], hp[4 * u + 1], hp[4 * u + 2], hp[4 * u + 3]);
      ld[u] = make_uint4(lp[4 * u], lp[4 * u + 1], lp[4 * u + 2], lp[4 * u + 3]);
    }
  }
}

// ---------------------------------------------------------------------------
// kB v5 (MFMA): agg[k][d] = sum_n A[k,n] * x[d,n], A = asT_hi+asT_lo (bf16
// split of softmax*invn, padded pitch Np), x converted to bf16 in-register.
// grid 512: b = bid>>5, dt = (bid>>3)&3 (128 d), seg = bid&7 (512 n).
// Writes aggp[seg][b][k][d] at padded pitch Dp.
// ---------------------------------------------------------------------------
__global__ __launch_bounds__(512) void kB(const float* __restrict__ x,
                                          const unsigned short* __restrict__ asT_hi,
                                          const unsigned short* __restrict__ asT_lo,
                                          float* __restrict__ aggp) {
  const int tid = threadIdx.x;
  const int l = tid & 63;
  const int w = tid >> 6;
  const int kw = w & 3;
  const int dh = w >> 2;
  const int b = blockIdx.x >> 5;
  const int dt = (blockIdx.x >> 3) & 3;
  const int seg = blockIdx.x & 7;
  const int lg = l >> 4;
  const int ll = l & 15;

  const size_t aoff =
      ((size_t)b * Kn + kw * 16 + ll) * Np + seg * 512 + lg * 8;
  const unsigned short* ah = asT_hi + aoff;
  const unsigned short* al = asT_lo + aoff;
  const int dbase = dt * 128 + dh * 64 + ll;
  const float* xp = x + (size_t)b * Dn * Nn + (size_t)dbase * Nn +
                    seg * 512 + lg * 8;

  f32x4 acc[4];
#pragma unroll
  for (int t = 0; t < 4; ++t) acc[t] = (f32x4){0.f, 0.f, 0.f, 0.f};

  for (int ns = 0; ns < 512; ns += 32) {
    bf16x8 av_h = *(const bf16x8*)(ah + ns);
    bf16x8 av_l = *(const bf16x8*)(al + ns);
#pragma unroll
    for (int t = 0; t < 4; ++t) {
      const float* xr = xp + (size_t)(t * 16) * Nn + ns;
      float4 x0 = *(const float4*)(xr);
      float4 x1 = *(const float4*)(xr + 4);
      bf16x8 bv;
      bv[0] = (__bf16)x0.x; bv[1] = (__bf16)x0.y;
      bv[2] = (__bf16)x0.z; bv[3] = (__bf16)x0.w;
      bv[4] = (__bf16)x1.x; bv[5] = (__bf16)x1.y;
      bv[6] = (__bf16)x1.z; bv[7] = (__bf16)x1.w;
      acc[t] = __builtin_amdgcn_mfma_f32_16x16x32_bf16(av_h, bv, acc[t], 0, 0, 0);
      acc[t] = __builtin_amdgcn_mfma_f32_16x16x32_bf16(av_l, bv, acc[t], 0, 0, 0);
    }
  }

  const int krow = kw * 16 + (lg << 2);
#pragma unroll
  for (int t = 0; t < 4; ++t) {
    const int dcol = dt * 128 + dh * 64 + t * 16 + ll;
    float* op = aggp + (((size_t)(seg * Bn + b)) * Kn + krow) * Dp + dcol;
#pragma unroll
    for (int r = 0; r < 4; ++r) op[(size_t)r * Dp] = acc[t][r];
  }
}

// ---------------------------------------------------------------------------
// kC1: per (b,k): mass from massp (16 panels); vlad = sum(aggp over 8 segs)
// - mass*c; intra-normalize over d.
// ---------------------------------------------------------------------------
__device__ __forceinline__ float blockReduceSum(float v, float* sb) {
#pragma unroll
  for (int off = 32; off > 0; off >>= 1) v += __shfl_down(v, off, 64);
  const int lane = threadIdx.x & 63, w = threadIdx.x >> 6;
  if (lane == 0) sb[w] = v;
  __syncthreads();
  if (threadIdx.x == 0) sb[4] = sb[0] + sb[1] + sb[2] + sb[3];
  __syncthreads();
  return sb[4];
}

__global__ __launch_bounds__(256) void kC1(const float* __restrict__ massp,
                                           const float* __restrict__ aggp,
                                           const float* __restrict__ centroids,
                                           float* __restrict__ out,
                                           float* __restrict__ rowsq) {
  __shared__ float sb[5];
  const int tid = threadIdx.x;
  const int b = blockIdx.x >> 6, k = blockIdx.x & 63;
  float s = 0.f;
  if (tid < 16) s = massp[((b << 4) + tid) * Kn + k];
  const float mass = blockReduceSum(s, sb);
  float v[2];
  float sq = 0.f;
#pragma unroll
  for (int u = 0; u < 2; ++u) {
    const int d = tid + (u << 8);
    float val = -mass * centroids[k * Dn + d];
#pragma unroll
    for (int seg = 0; seg < 8; ++seg)
      val += aggp[(((size_t)seg * Bn + b) * Kn + k) * Dp + d];
    v[u] = val;
    sq = fmaf(val, val, sq);
  }
  const float rsq = blockReduceSum(sq, sb);
  const float inv = 1.f / fmaxf(sqrtf(rsq), FEPS);
#pragma unroll
  for (int u = 0; u < 2; ++u)
    out[((size_t)b * Kn + k) * Dn + tid + (u << 8)] = v[u] * inv;
  if (tid == 0) rowsq[b * Kn + k] = rsq * inv * inv;
}

// ---------------------------------------------------------------------------
// kC2: final global L2 norm per batch.
// ---------------------------------------------------------------------------
__global__ __launch_bounds__(256) void kC2(float* __restrict__ out,
                                           const float* __restrict__ rowsq) {
  __shared__ float sg;
  const int b = blockIdx.x, tid = threadIdx.x;
  float v = (tid < 64) ? rowsq[b * Kn + tid] : 0.f;
  if (tid < 64) {
#pragma unroll
    for (int off = 32; off > 0; off >>= 1) v += __shfl_down(v, off, 64);
  }
  if (tid == 0) sg = 1.f / fmaxf(sqrtf(v), FEPS);
  __syncthreads();
  const float inv = sg;
  float* ob = out + (size_t)b * (Kn * Dn);
  for (int t = tid; t < Kn * Dn; t += 256) ob[t] *= inv;
}

// ---------------------------------------------------------------------------
extern "C" void kernel_launch(void* const* d_in, const int* in_sizes, int n_in,
                              void* d_out, int out_size, void* d_ws,
                              size_t ws_size, hipStream_t stream) {
  const float* x = (const float*)d_in[0];
  const float* centroids = (const float*)d_in[1];
  const float* conv_w = (const float*)d_in[2];
  const float* conv_b = (const float*)d_in[3];
  float* out = (float*)d_out;
  float* ws = (float*)d_ws;
  // ws layout (float units):
  //   aggp    [0,        4325376)  8 segs x 16 x 64 x Dp(528)
  //   asT_hi  [4325376,  6488064)  16 x 64 x Np(4224) bf16
  //   asT_lo  [6488064,  8650752)
  //   w_hi    [8650752,  8667136)  64x512 bf16 = 16384 floats
  //   w_lo    [8667136,  8683520)  64x512 bf16 = 16384 floats
  //   massp   [8683520,  8699904)  16 b x 16 panels x 64 k
  //   rowsq   [8699904,  8700928)
  float* aggp = ws;
  unsigned short* asT_hi = (unsigned short*)(ws + 4325376);
  unsigned short* asT_lo = (unsigned short*)(ws + 6488064);
  unsigned short* w_hi = (unsigned short*)(ws + 8650752);
  unsigned short* w_lo = (unsigned short*)(ws + 8667136);
  float* massp = ws + 8683520;
  float* rowsq = ws + 8699904;

  kW<<<128, 256, 0, stream>>>(conv_w, w_hi, w_lo);
  kA<<<256, 512, 0, stream>>>(x, w_hi, w_lo, conv_b, asT_hi, asT_lo, massp);
  kB<<<512, 512, 0, stream>>>(x, asT_hi, asT_lo, aggp);
  kC1<<<1024, 256, 0, stream>>>(massp, aggp, centroids, out, rowsq);
  kC2<<<16, 256, 0, stream>>>(out, rowsq);
}

// Round 9
// 136.124 us; speedup vs baseline: 1.5004x; 1.2496x over previous
//
#include <hip/hip_runtime.h>
#include <cstddef>

constexpr int Bn = 16, Dn = 512, Nn = 4096, Kn = 64;
constexpr float FEPS = 1e-12f;

typedef __bf16 bf16x8 __attribute__((ext_vector_type(8)));
typedef float f32x4 __attribute__((ext_vector_type(4)));

__device__ __forceinline__ unsigned short bf_bits(__bf16 h) {
  union { __bf16 b; unsigned short u; } c;
  c.b = h;
  return c.u;
}

// ---------------------------------------------------------------------------
// kW: split conv_w[K][D] (row-major, d-contiguous) into bf16 hi/lo arrays.
// ---------------------------------------------------------------------------
__global__ __launch_bounds__(256) void kW(const float* __restrict__ w,
                                          unsigned short* __restrict__ w_hi,
                                          unsigned short* __restrict__ w_lo) {
  const int idx = blockIdx.x * 256 + threadIdx.x;  // 32768 total
  const float v = w[idx];
  const __bf16 h = (__bf16)v;          // RNE
  const float r = v - (float)h;
  const __bf16 l = (__bf16)r;
  w_hi[idx] = bf_bits(h);
  w_lo[idx] = bf_bits(l);
}

// ---------------------------------------------------------------------------
// kF: FUSED logits+softmax+agg kernel. One block = one (b, 256-n panel),
// 1024 threads = 16 waves (4 waves/SIMD).
// Phase 1 (kA v6 math, validated): logits[k][n] = sum_d W[k,d]*x[d,n] via
//   3-term bf16-split MFMA; x read in full 1KB rows, transposed through
//   double-buffered LDS (pitch 33, 1 barrier/chunk). Softmax in-register.
//   Wave wv owns the 16-n subtile wv*16.
// Inter-phase: assign*invn stored hi/lo bf16 in LDS, layout [ngrp32][k64][8]
//   (A-frag native: 16B-aligned contiguous per-lane reads).
// Phase 2: agg[k][d] partial = sum_{n in panel} assign[k,n]*x[d,n].
//   A-frags from LDS, B = x[d][n] re-read from L2/L3 (panel is hot),
//   converted to bf16 (hi) in-register — same numerics as validated kB.
//   Wave wv owns d-slice wv*32 (2 tiles of 16).
// Writes: aggp[b][p][64][512] partials, massp[b][p][64].
// ---------------------------------------------------------------------------
__global__ __launch_bounds__(1024) void kF(const float* __restrict__ x,
                                           const unsigned short* __restrict__ w_hi,
                                           const unsigned short* __restrict__ w_lo,
                                           const float* __restrict__ conv_b,
                                           float* __restrict__ aggp,
                                           float* __restrict__ massp) {
  __shared__ float smem[2 * 256 * 33];  // 67.6 KB: xs double-buffer; reused
                                        // as assign hi(32KB)+lo(32KB)
  __shared__ float msum[16][64];
  const int tid = threadIdx.x;
  const int l = tid & 63;
  const int wv = tid >> 6;   // 0..15
  const int ll = l & 15;
  const int lg = l >> 4;
  const int b = blockIdx.x >> 4;
  const int p = blockIdx.x & 15;
  const int n0 = p << 8;
  const float* xb = x + (size_t)b * Dn * Nn + n0;

  // ===================== Phase 1: logits =====================
  f32x4 acc[4];
#pragma unroll
  for (int kt = 0; kt < 4; ++kt) acc[kt] = (f32x4){0.f, 0.f, 0.f, 0.f};
  float ss = 0.f;

  // prefetch chunk 0: wave wv loads rows {wv, wv+16}, lane sweeps 256 cols
  float pf[2][4];
#pragma unroll
  for (int i = 0; i < 2; ++i)
#pragma unroll
    for (int q = 0; q < 4; ++q)
      pf[i][q] = xb[(size_t)(wv + 16 * i) * Nn + l + 64 * q];

  for (int dc = 0; dc < Dn; dc += 32) {
    float* xs = smem + ((dc >> 5) & 1) * (256 * 33);
#pragma unroll
    for (int i = 0; i < 2; ++i)
#pragma unroll
      for (int q = 0; q < 4; ++q)
        xs[(l + 64 * q) * 33 + wv + 16 * i] = pf[i][q];
    if (dc + 32 < Dn) {
#pragma unroll
      for (int i = 0; i < 2; ++i)
#pragma unroll
        for (int q = 0; q < 4; ++q)
          pf[i][q] = xb[(size_t)(dc + 32 + wv + 16 * i) * Nn + l + 64 * q];
    }
    __syncthreads();  // xs(chunk) ready; prev buffer free next iter

    const int ncol = (wv << 4) + ll;
    float xv[8];
#pragma unroll
    for (int j = 0; j < 8; ++j) xv[j] = xs[ncol * 33 + lg * 8 + j];
    bf16x8 bh, bl;
#pragma unroll
    for (int j = 0; j < 8; ++j) {
      ss = fmaf(xv[j], xv[j], ss);
      const __bf16 h = (__bf16)xv[j];
      bh[j] = h;
      bl[j] = (__bf16)(xv[j] - (float)h);
    }
#pragma unroll
    for (int kt = 0; kt < 4; ++kt) {
      const size_t woff = (size_t)(kt * 16 + ll) * Dn + dc + lg * 8;
      bf16x8 ah = *(const bf16x8*)(w_hi + woff);
      bf16x8 al = *(const bf16x8*)(w_lo + woff);
      acc[kt] = __builtin_amdgcn_mfma_f32_16x16x32_bf16(ah, bh, acc[kt], 0, 0, 0);
      acc[kt] = __builtin_amdgcn_mfma_f32_16x16x32_bf16(ah, bl, acc[kt], 0, 0, 0);
      acc[kt] = __builtin_amdgcn_mfma_f32_16x16x32_bf16(al, bh, acc[kt], 0, 0, 0);
    }
  }

  // ---- softmax (in-register, per 16-n subtile) ----
  ss += __shfl_xor(ss, 16);
  ss += __shfl_xor(ss, 32);
  const float iv = 1.f / fmaxf(sqrtf(ss), FEPS);
  float lgt[16];
#pragma unroll
  for (int kt = 0; kt < 4; ++kt)
#pragma unroll
    for (int r = 0; r < 4; ++r)
      lgt[kt * 4 + r] = fmaf(acc[kt][r], iv, conv_b[kt * 16 + lg * 4 + r]);
  float pmax = lgt[0];
#pragma unroll
  for (int i = 1; i < 16; ++i) pmax = fmaxf(pmax, lgt[i]);
  pmax = fmaxf(pmax, __shfl_xor(pmax, 16));
  pmax = fmaxf(pmax, __shfl_xor(pmax, 32));
  float ex[16];
  float psum = 0.f;
#pragma unroll
  for (int i = 0; i < 16; ++i) {
    ex[i] = expf(lgt[i] - pmax);
    psum += ex[i];
  }
  psum += __shfl_xor(psum, 16);
  psum += __shfl_xor(psum, 32);
  const float isum = 1.f / psum;

  __syncthreads();  // all xs reads done before smem reused as assign

  // ---- assign hi/lo bf16 into LDS ([ngrp][k][8]) + mass partials ----
  unsigned short* as_hi = (unsigned short*)smem;
  unsigned short* as_lo = as_hi + 16384;
  const int ngb = (wv << 1) + (ll >> 3);
  const int jj = ll & 7;
#pragma unroll
  for (int i = 0; i < 16; ++i) {
    const int k = (i >> 2) * 16 + lg * 4 + (i & 3);
    const float a = ex[i] * isum;
    const float v = a * iv;
    const __bf16 h = (__bf16)v;
    as_hi[(ngb * 64 + k) * 8 + jj] = bf_bits(h);
    as_lo[(ngb * 64 + k) * 8 + jj] = bf_bits((__bf16)(v - (float)h));
    float m = a;
    m += __shfl_xor(m, 1);
    m += __shfl_xor(m, 2);
    m += __shfl_xor(m, 4);
    m += __shfl_xor(m, 8);
    if (ll == 0) msum[wv][k] = m;
  }
  __syncthreads();  // assign + msum visible to all
  if (tid < 64) {
    float s = 0.f;
#pragma unroll
    for (int ww = 0; ww < 16; ++ww) s += msum[ww][tid];
    massp[((b << 4) + p) * Kn + tid] = s;
  }

  // ===================== Phase 2: agg partial =====================
  // wave wv -> d in [wv*32, wv*32+32); M=k, N=d, K=n(panel)
  f32x4 acc2[4][2];
#pragma unroll
  for (int kt = 0; kt < 4; ++kt)
#pragma unroll
    for (int dt = 0; dt < 2; ++dt) acc2[kt][dt] = (f32x4){0.f, 0.f, 0.f, 0.f};

  const float* xq0 = x + (size_t)b * Dn * Nn +
                     (size_t)(wv * 32 + ll) * Nn + n0 + lg * 8;
  const float* xq1 = xq0 + (size_t)16 * Nn;

#pragma unroll 2
  for (int nc = 0; nc < 256; nc += 32) {
    const int ng = (nc >> 3) + lg;
    bf16x8 af_h[4], af_l[4];
#pragma unroll
    for (int kt = 0; kt < 4; ++kt) {
      const int idx = (ng * 64 + kt * 16 + ll) * 8;
      af_h[kt] = *(const bf16x8*)(as_hi + idx);
      af_l[kt] = *(const bf16x8*)(as_lo + idx);
    }
    bf16x8 bx[2];
#pragma unroll
    for (int dt = 0; dt < 2; ++dt) {
      const float* xr = (dt == 0 ? xq0 : xq1) + nc;
      float4 x0 = *(const float4*)(xr);
      float4 x1 = *(const float4*)(xr + 4);
      bx[dt][0] = (__bf16)x0.x; bx[dt][1] = (__bf16)x0.y;
      bx[dt][2] = (__bf16)x0.z; bx[dt][3] = (__bf16)x0.w;
      bx[dt][4] = (__bf16)x1.x; bx[dt][5] = (__bf16)x1.y;
      bx[dt][6] = (__bf16)x1.z; bx[dt][7] = (__bf16)x1.w;
    }
#pragma unroll
    for (int kt = 0; kt < 4; ++kt)
#pragma unroll
      for (int dt = 0; dt < 2; ++dt) {
        acc2[kt][dt] =
            __builtin_amdgcn_mfma_f32_16x16x32_bf16(af_h[kt], bx[dt], acc2[kt][dt], 0, 0, 0);
        acc2[kt][dt] =
            __builtin_amdgcn_mfma_f32_16x16x32_bf16(af_l[kt], bx[dt], acc2[kt][dt], 0, 0, 0);
      }
  }

  // store partials: aggp[((b*16+p)*64 + k)*512 + d]
  float* outb = aggp + ((size_t)((b << 4) + p) * Kn) * Dn;
#pragma unroll
  for (int kt = 0; kt < 4; ++kt)
#pragma unroll
    for (int dt = 0; dt < 2; ++dt) {
      const int krow = kt * 16 + (lg << 2);
      const int dcol = wv * 32 + dt * 16 + ll;
      float* op = outb + (size_t)krow * Dn + dcol;
#pragma unroll
      for (int r = 0; r < 4; ++r) op[(size_t)r * Dn] = acc2[kt][dt][r];
    }
}

// ---------------------------------------------------------------------------
// kC1: per (b,k): mass from massp (16 panels); vlad = sum(aggp over 16
// panels) - mass*c; intra-normalize over d.
// ---------------------------------------------------------------------------
__device__ __forceinline__ float blockReduceSum(float v, float* sb) {
#pragma unroll
  for (int off = 32; off > 0; off >>= 1) v += __shfl_down(v, off, 64);
  const int lane = threadIdx.x & 63, w = threadIdx.x >> 6;
  if (lane == 0) sb[w] = v;
  __syncthreads();
  if (threadIdx.x == 0) sb[4] = sb[0] + sb[1] + sb[2] + sb[3];
  __syncthreads();
  return sb[4];
}

__global__ __launch_bounds__(256) void kC1(const float* __restrict__ massp,
                                           const float* __restrict__ aggp,
                                           const float* __restrict__ centroids,
                                           float* __restrict__ out,
                                           float* __restrict__ rowsq) {
  __shared__ float sb[5];
  const int tid = threadIdx.x;
  const int b = blockIdx.x >> 6, k = blockIdx.x & 63;
  float s = 0.f;
  if (tid < 16) s = massp[((b << 4) + tid) * Kn + k];
  const float mass = blockReduceSum(s, sb);
  float v[2];
  float sq = 0.f;
#pragma unroll
  for (int u = 0; u < 2; ++u) {
    const int d = tid + (u << 8);
    float val = -mass * centroids[k * Dn + d];
#pragma unroll
    for (int pp = 0; pp < 16; ++pp)
      val += aggp[((size_t)((b << 4) + pp) * Kn + k) * Dn + d];
    v[u] = val;
    sq = fmaf(val, val, sq);
  }
  const float rsq = blockReduceSum(sq, sb);
  const float inv = 1.f / fmaxf(sqrtf(rsq), FEPS);
#pragma unroll
  for (int u = 0; u < 2; ++u)
    out[((size_t)b * Kn + k) * Dn + tid + (u << 8)] = v[u] * inv;
  if (tid == 0) rowsq[b * Kn + k] = rsq * inv * inv;
}

// ---------------------------------------------------------------------------
// kC2: final global L2 norm per batch.
// ---------------------------------------------------------------------------
__global__ __launch_bounds__(256) void kC2(float* __restrict__ out,
                                           const float* __restrict__ rowsq) {
  __shared__ float sg;
  const int b = blockIdx.x, tid = threadIdx.x;
  float v = (tid < 64) ? rowsq[b * Kn + tid] : 0.f;
  if (tid < 64) {
#pragma unroll
    for (int off = 32; off > 0; off >>= 1) v += __shfl_down(v, off, 64);
  }
  if (tid == 0) sg = 1.f / fmaxf(sqrtf(v), FEPS);
  __syncthreads();
  const float inv = sg;
  float* ob = out + (size_t)b * (Kn * Dn);
  for (int t = tid; t < Kn * Dn; t += 256) ob[t] *= inv;
}

// ---------------------------------------------------------------------------
extern "C" void kernel_launch(void* const* d_in, const int* in_sizes, int n_in,
                              void* d_out, int out_size, void* d_ws,
                              size_t ws_size, hipStream_t stream) {
  const float* x = (const float*)d_in[0];
  const float* centroids = (const float*)d_in[1];
  const float* conv_w = (const float*)d_in[2];
  const float* conv_b = (const float*)d_in[3];
  float* out = (float*)d_out;
  float* ws = (float*)d_ws;
  // ws layout (float units):
  //   aggp    [0,        8388608)  16 b x 16 p x 64 k x 512 d f32
  //   w_hi    [8388608,  8404992)  64x512 bf16 = 16384 floats
  //   w_lo    [8404992,  8421376)
  //   massp   [8421376,  8437760)  16 b x 16 p x 64 k
  //   rowsq   [8437760,  8438784)
  float* aggp = ws;
  unsigned short* w_hi = (unsigned short*)(ws + 8388608);
  unsigned short* w_lo = (unsigned short*)(ws + 8404992);
  float* massp = ws + 8421376;
  float* rowsq = ws + 8437760;

  kW<<<128, 256, 0, stream>>>(conv_w, w_hi, w_lo);
  kF<<<256, 1024, 0, stream>>>(x, w_hi, w_lo, conv_b, aggp, massp);
  kC1<<<1024, 256, 0, stream>>>(massp, aggp, centroids, out, rowsq);
  kC2<<<16, 256, 0, stream>>>(out, rowsq);
}